// Round 1
// baseline (1067.026 us; speedup 1.0000x reference)
//
#include <hip/hip_runtime.h>
#include <hip/hip_bf16.h>

typedef unsigned short u16;
typedef unsigned int u32;
typedef __bf16 bf16x8 __attribute__((ext_vector_type(8)));
typedef float f32x4 __attribute__((ext_vector_type(4)));
typedef u16 u16x8 __attribute__((ext_vector_type(8)));

#define B_ 2
#define S_ 2048
#define NH 32
#define NKV 8
#define HD 128
#define DIM_ 4096

__device__ inline u16 f2b(float f) {
  u32 u = __builtin_bit_cast(u32, f);
  u = (u + 0x7fffu + ((u >> 16) & 1u)) >> 16;
  return (u16)u;
}
__device__ inline float b2f(u16 b) {
  u32 u = ((u32)b) << 16;
  return __builtin_bit_cast(float, u);
}

// ---------------- f32 -> bf16 cast ----------------
__global__ __launch_bounds__(256) void k_f32_to_bf16(const float* __restrict__ in,
                                                     u16* __restrict__ out, int n4) {
  int i = blockIdx.x * 256 + threadIdx.x;
  if (i >= n4) return;
  const float4 v = ((const float4*)in)[i];
  u32 lo = (u32)f2b(v.x) | ((u32)f2b(v.y) << 16);
  u32 hi = (u32)f2b(v.z) | ((u32)f2b(v.w) << 16);
  ((u32*)out)[(size_t)i * 2] = lo;
  ((u32*)out)[(size_t)i * 2 + 1] = hi;
}

// ---------------- GEMM: C[M][N] = A[M][K] * B[N][K]^T, bf16 in, f32 acc ----------------
template <int OUTF32>
__global__ __launch_bounds__(256) void k_gemm_bt(const u16* __restrict__ A,
                                                 const u16* __restrict__ Bm,
                                                 void* __restrict__ Cout,
                                                 int M, int N, int K) {
  constexpr int BK = 64, LDT = 72;  // +8 bf16 pad
  __shared__ u16 As[128][LDT];
  __shared__ u16 Bs[128][LDT];
  const int tid = threadIdx.x;
  const int lane = tid & 63, wid = tid >> 6;
  const int wr = wid >> 1, wc = wid & 1;
  const int lr = lane & 15, lg = lane >> 4;
  const int m0 = blockIdx.x * 128, n0 = blockIdx.y * 128;
  f32x4 acc[4][4] = {};
  const int srow = tid >> 3, scol = (tid & 7) * 8;
  const u16* ap = A + (size_t)(m0 + srow) * K + scol;
  const u16* bp = Bm + (size_t)(n0 + srow) * K + scol;
  for (int k0 = 0; k0 < K; k0 += BK) {
#pragma unroll
    for (int i = 0; i < 4; ++i) {
      *(u16x8*)&As[srow + 32 * i][scol] = *(const u16x8*)(ap + (size_t)(32 * i) * K + k0);
      *(u16x8*)&Bs[srow + 32 * i][scol] = *(const u16x8*)(bp + (size_t)(32 * i) * K + k0);
    }
    __syncthreads();
#pragma unroll
    for (int ks = 0; ks < 2; ++ks) {
      bf16x8 af[4], bfr[4];
#pragma unroll
      for (int mi = 0; mi < 4; ++mi)
        af[mi] = *(const bf16x8*)&As[wr * 64 + mi * 16 + lr][ks * 32 + lg * 8];
#pragma unroll
      for (int ni = 0; ni < 4; ++ni)
        bfr[ni] = *(const bf16x8*)&Bs[wc * 64 + ni * 16 + lr][ks * 32 + lg * 8];
#pragma unroll
      for (int mi = 0; mi < 4; ++mi)
#pragma unroll
        for (int ni = 0; ni < 4; ++ni)
          acc[mi][ni] = __builtin_amdgcn_mfma_f32_16x16x32_bf16(af[mi], bfr[ni], acc[mi][ni], 0, 0, 0);
    }
    __syncthreads();
  }
  // D layout: col = lane&15, row = (lane>>4)*4 + j  [m89/m91]
#pragma unroll
  for (int mi = 0; mi < 4; ++mi) {
    const int r = m0 + wr * 64 + mi * 16 + lg * 4;
#pragma unroll
    for (int ni = 0; ni < 4; ++ni) {
      const int cc = n0 + wc * 64 + ni * 16 + lr;
#pragma unroll
      for (int j = 0; j < 4; ++j) {
        float v = acc[mi][ni][j];
        if (OUTF32)
          ((float*)Cout)[(size_t)(r + j) * N + cc] = v;
        else
          ((u16*)Cout)[(size_t)(r + j) * N + cc] = f2b(v);
      }
    }
  }
}

// ---------------- RoPE + permute [B][S][H][D] -> [B][H][S][D] ----------------
__global__ __launch_bounds__(256) void k_rope_perm(const u16* __restrict__ src,
                                                   u16* __restrict__ dst,
                                                   const float* __restrict__ cosb,
                                                   const float* __restrict__ sinb, int H) {
  const int row = blockIdx.x * 4 + (threadIdx.x >> 6);  // row = (b*H + h)*S + s
  const int lane = threadIdx.x & 63;
  const int s = row & (S_ - 1);
  const int h = (row >> 11) % H;
  const int b = row / (S_ * H);
  const u16* sp = src + (((size_t)b * S_ + s) * H + h) * HD + lane * 2;
  const u32 u = *(const u32*)sp;
  const float f0 = b2f((u16)(u & 0xffffu));
  const float f1 = b2f((u16)(u >> 16));
  const float c = cosb[s * 64 + lane];
  const float sn = sinb[s * 64 + lane];
  const float r0 = f0 * c - f1 * sn;
  const float r1 = f0 * sn + f1 * c;
  const u32 o = (u32)f2b(r0) | ((u32)f2b(r1) << 16);
  *(u32*)(dst + (size_t)row * HD + lane * 2) = o;
}

// ---------------- V transpose: [B][S][NKV][HD] -> [B][NKV][HD][S] ----------------
__global__ __launch_bounds__(256) void k_transpose_v(const u16* __restrict__ vp,
                                                     u16* __restrict__ vt) {
  __shared__ u16 tile[64][72];
  const int s0 = blockIdx.x * 64, d0 = blockIdx.y * 64;
  const int b = blockIdx.z >> 3, kvh = blockIdx.z & 7;
  const int tid = threadIdx.x;
  const int r = tid >> 3, c8 = (tid & 7) * 8;
#pragma unroll
  for (int i = 0; i < 2; ++i) {
    const int sl = r + 32 * i;
    *(u16x8*)&tile[sl][c8] =
        *(const u16x8*)&vp[(((size_t)b * S_ + s0 + sl) * NKV + kvh) * HD + d0 + c8];
  }
  __syncthreads();
#pragma unroll
  for (int i = 0; i < 2; ++i) {
    const int dl = r + 32 * i;
    u16x8 o;
#pragma unroll
    for (int j = 0; j < 8; ++j) o[j] = tile[c8 + j][dl];
    *(u16x8*)&vt[(((size_t)b * NKV + kvh) * HD + d0 + dl) * S_ + s0 + c8] = o;
  }
}

// ---------------- Flash attention, causal, GQA rep=4 ----------------
// Q: [B][NH][S][HD], K: [B][NKV][S][HD], Vt: [B][NKV][HD][S], O: [B][S][NH*HD]
__global__ __launch_bounds__(256) void k_attn(const u16* __restrict__ Qg,
                                              const u16* __restrict__ Kg,
                                              const u16* __restrict__ Vtg,
                                              u16* __restrict__ Og) {
  constexpr int QB = 64, KB = 64;
  __shared__ u16 Ks[KB][HD + 8];
  __shared__ u16 Vs[HD][KB + 8];
  __shared__ u16 Ps[4][16][KB + 8];  // per-wave private P
  const int qt = blockIdx.x, h = blockIdx.y, b = blockIdx.z;
  const int kvh = h >> 2;
  const int tid = threadIdx.x, wid = tid >> 6, lane = tid & 63;
  const int lr = lane & 15, lg = lane >> 4;
  const int q0 = qt * QB;
  // Q fragments held in registers for the whole block
  const u16* qp = Qg + (((size_t)b * NH + h) * S_ + q0 + wid * 16 + lr) * HD + lg * 8;
  bf16x8 qf[4];
#pragma unroll
  for (int ks = 0; ks < 4; ++ks) qf[ks] = *(const bf16x8*)(qp + ks * 32);
  f32x4 o[8] = {};
  float mrun[4], lrun[4];
#pragma unroll
  for (int j = 0; j < 4; ++j) { mrun[j] = -1e30f; lrun[j] = 0.f; }
  const u16* kb = Kg + ((size_t)b * NKV + kvh) * (size_t)S_ * HD;
  const u16* vb = Vtg + ((size_t)b * NKV + kvh) * (size_t)HD * S_;
  const int krow = tid >> 4, kcol = (tid & 15) * 8;
  const int vrow = tid >> 3, vcol = (tid & 7) * 8;
  for (int t = 0; t <= qt; ++t) {
    __syncthreads();
#pragma unroll
    for (int i = 0; i < 4; ++i)
      *(u16x8*)&Ks[krow + 16 * i][kcol] =
          *(const u16x8*)&kb[(size_t)(t * KB + krow + 16 * i) * HD + kcol];
#pragma unroll
    for (int i = 0; i < 4; ++i)
      *(u16x8*)&Vs[vrow + 32 * i][vcol] =
          *(const u16x8*)&vb[(size_t)(vrow + 32 * i) * S_ + t * KB + vcol];
    __syncthreads();
    // S = Q K^T  (16x64 per wave)
    f32x4 s[4] = {};
#pragma unroll
    for (int ks = 0; ks < 4; ++ks)
#pragma unroll
      for (int n = 0; n < 4; ++n) {
        bf16x8 kf = *(const bf16x8*)&Ks[n * 16 + lr][ks * 32 + lg * 8];
        s[n] = __builtin_amdgcn_mfma_f32_16x16x32_bf16(qf[ks], kf, s[n], 0, 0, 0);
      }
    const float scale = 0.08838834764831845f;
    float sv[4][4], pm[4];
#pragma unroll
    for (int j = 0; j < 4; ++j) pm[j] = -1e30f;
    const bool diag = (t == qt);
#pragma unroll
    for (int n = 0; n < 4; ++n)
#pragma unroll
      for (int j = 0; j < 4; ++j) {
        float v = s[n][j] * scale;
        if (diag && (n * 16 + lr > wid * 16 + lg * 4 + j)) v = -1e30f;  // causal
        sv[n][j] = v;
        pm[j] = fmaxf(pm[j], v);
      }
#pragma unroll
    for (int off = 1; off < 16; off <<= 1)
#pragma unroll
      for (int j = 0; j < 4; ++j) pm[j] = fmaxf(pm[j], __shfl_xor(pm[j], off));
    float al[4];
#pragma unroll
    for (int j = 0; j < 4; ++j) {
      const float mt = fmaxf(mrun[j], pm[j]);
      al[j] = __expf(mrun[j] - mt);
      mrun[j] = mt;
    }
    float ls[4] = {0.f, 0.f, 0.f, 0.f};
#pragma unroll
    for (int n = 0; n < 4; ++n)
#pragma unroll
      for (int j = 0; j < 4; ++j) {
        const float p = __expf(sv[n][j] - mrun[j]);
        ls[j] += p;
        Ps[wid][lg * 4 + j][n * 16 + lr] = f2b(p);
      }
#pragma unroll
    for (int off = 1; off < 16; off <<= 1)
#pragma unroll
      for (int j = 0; j < 4; ++j) ls[j] += __shfl_xor(ls[j], off);
#pragma unroll
    for (int j = 0; j < 4; ++j) lrun[j] = lrun[j] * al[j] + ls[j];
#pragma unroll
    for (int c = 0; c < 8; ++c)
#pragma unroll
      for (int j = 0; j < 4; ++j) o[c][j] *= al[j];
    // wave-private LDS RAW: ensure P writes complete & aren't reordered
    asm volatile("s_waitcnt lgkmcnt(0)" ::: "memory");
    // O += P V   (16x128 per wave)
#pragma unroll
    for (int ks = 0; ks < 2; ++ks) {
      bf16x8 af = *(const bf16x8*)&Ps[wid][lr][ks * 32 + lg * 8];
#pragma unroll
      for (int c = 0; c < 8; ++c) {
        bf16x8 vf = *(const bf16x8*)&Vs[c * 16 + lr][ks * 32 + lg * 8];
        o[c] = __builtin_amdgcn_mfma_f32_16x16x32_bf16(af, vf, o[c], 0, 0, 0);
      }
    }
  }
#pragma unroll
  for (int c = 0; c < 8; ++c)
#pragma unroll
    for (int j = 0; j < 4; ++j) {
      const int srow = q0 + wid * 16 + lg * 4 + j;
      const float v = o[c][j] / lrun[j];
      Og[((size_t)b * S_ + srow) * (NH * HD) + h * HD + c * 16 + lr] = f2b(v);
    }
}

extern "C" void kernel_launch(void* const* d_in, const int* in_sizes, int n_in,
                              void* d_out, int out_size, void* d_ws, size_t ws_size,
                              hipStream_t stream) {
  const float* x = (const float*)d_in[0];
  const float* fc = (const float*)d_in[1];
  const float* fs = (const float*)d_in[2];
  // d_in[3] positions (identity), d_in[4] mask (pure causal) -- applied analytically
  const float* wq = (const float*)d_in[5];
  const float* wk = (const float*)d_in[6];
  const float* wv = (const float*)d_in[7];
  const float* wo = (const float*)d_in[8];
  char* ws = (char*)d_ws;
  u16* xb = (u16*)(ws);                    // 33,554,432 B
  u16* wqb = (u16*)(ws + 33554432);        // 33,554,432 B
  u16* wkb = (u16*)(ws + 67108864);        // 8,388,608 B
  u16* wvb = (u16*)(ws + 75497472);        // 8,388,608 B
  u16* wob = (u16*)(ws + 83886080);        // 33,554,432 B
  u16* qp = (u16*)(ws + 117440512);        // 33,554,432 B
  u16* kp = (u16*)(ws + 150994944);        // 8,388,608 B
  u16* vp = (u16*)(ws + 159383552);        // 8,388,608 B -> ends at 167,772,160
  // reuse after liveness ends:
  u16* Q = wqb;     // [B][NH][S][HD]
  u16* Kr = wkb;    // [B][NKV][S][HD]
  u16* Vt = wvb;    // [B][NKV][HD][S]
  u16* attn = xb;   // [B*S][NH*HD]
  float* out = (float*)d_out;

  k_f32_to_bf16<<<16384, 256, 0, stream>>>(x, xb, 4194304);
  k_f32_to_bf16<<<16384, 256, 0, stream>>>(wq, wqb, 4194304);
  k_f32_to_bf16<<<4096, 256, 0, stream>>>(wk, wkb, 1048576);
  k_f32_to_bf16<<<4096, 256, 0, stream>>>(wv, wvb, 1048576);
  k_f32_to_bf16<<<16384, 256, 0, stream>>>(wo, wob, 4194304);

  k_gemm_bt<0><<<dim3(32, 32), 256, 0, stream>>>(xb, wqb, qp, 4096, 4096, 4096);
  k_gemm_bt<0><<<dim3(32, 8), 256, 0, stream>>>(xb, wkb, kp, 4096, 1024, 4096);
  k_gemm_bt<0><<<dim3(32, 8), 256, 0, stream>>>(xb, wvb, vp, 4096, 1024, 4096);

  k_rope_perm<<<32768, 256, 0, stream>>>(qp, Q, fc, fs, NH);
  k_rope_perm<<<8192, 256, 0, stream>>>(kp, Kr, fc, fs, NKV);
  k_transpose_v<<<dim3(32, 2, 16), 256, 0, stream>>>(vp, Vt);

  k_attn<<<dim3(32, 32, 2), 256, 0, stream>>>(Q, Kr, Vt, attn);

  k_gemm_bt<1><<<dim3(32, 32), 256, 0, stream>>>(attn, wob, out, 4096, 4096, 4096);
}